// Round 4
// baseline (244.605 us; speedup 1.0000x reference)
//
#include <hip/hip_runtime.h>
#include <math.h>

// Problem constants (MAB_50921132261692)
#define Bx  4
#define NQx 2048
#define NKx 2048
#define Dx  512
#define Hx  8

typedef __attribute__((ext_vector_type(8))) __bf16 bf16x8;
typedef __attribute__((ext_vector_type(4))) float f32x4;
typedef __attribute__((ext_vector_type(16))) float f32x16;

typedef const __attribute__((address_space(1))) unsigned int* gas_ptr;
typedef __attribute__((address_space(3))) unsigned int* lds_ptr;

__device__ __forceinline__ void gload16(const void* g, void* l){
  __builtin_amdgcn_global_load_lds((gas_ptr)g, (lds_ptr)l, 16, 0, 0);
}

__device__ __forceinline__ unsigned short f2bf(float f){
  union { float f; unsigned int u; } v; v.f = f;
  unsigned int r = (v.u + 0x7FFFu + ((v.u >> 16) & 1u)) >> 16;
  return (unsigned short)r;
}
__device__ __forceinline__ float bf2f(unsigned short u){
  union { unsigned int u; float f; } v; v.u = ((unsigned int)u) << 16; return v.f;
}
__device__ __forceinline__ unsigned int cvtpk_bf16(float a, float b){
  unsigned int d;
  asm("v_cvt_pk_bf16_f32 %0, %1, %2" : "=v"(d) : "v"(a), "v"(b));
  return d;
}
__device__ __forceinline__ void plane32_swap(unsigned int& a, unsigned int& b){
  asm("v_permlane32_swap_b32 %0, %1" : "+v"(a), "+v"(b));
}
__device__ __forceinline__ float fexp2(float x){           // D = 2^x
  float d; asm("v_exp_f32 %0, %1" : "=v"(d) : "v"(x)); return d;
}
__device__ __forceinline__ float fmax3(float a, float b, float c){
  float d; asm("v_max3_f32 %0, %1, %2, %3" : "=v"(d) : "v"(a), "v"(b), "v"(c)); return d;
}

// ---------------------------------------------------------------------------
// Transpose + convert 5 weights [512][512] f32 -> Wt bf16 [z][N=512][K=512].
// ---------------------------------------------------------------------------
__global__ __launch_bounds__(256) void mab_wt(
    const float* __restrict__ Wq, const float* __restrict__ Wk, const float* __restrict__ Wv,
    const float* __restrict__ W0, const float* __restrict__ W1,
    unsigned short* __restrict__ Wt)
{
  __shared__ unsigned short T[64][72];
  const int z = blockIdx.z;
  const float* W = (z==0)?Wq:(z==1)?Wk:(z==2)?Wv:(z==3)?W0:W1;
  unsigned short* O = Wt + (size_t)z*512*512;
  const int k0 = blockIdx.x*64, n0 = blockIdx.y*64;
  const int tid = threadIdx.x;
  #pragma unroll
  for (int i=0;i<4;++i){
    int id = tid + i*256;          // 1024 = 64 rows x 16 float4
    int r = id>>4, c4 = id&15;
    float4 v = *(const float4*)(W + (size_t)(k0+r)*512 + n0 + c4*4);
    ushort4 o; o.x=f2bf(v.x); o.y=f2bf(v.y); o.z=f2bf(v.z); o.w=f2bf(v.w);
    *(ushort4*)&T[r][c4*4] = o;
  }
  __syncthreads();
  #pragma unroll
  for (int i=0;i<2;++i){
    int id = tid + i*256;          // 512 = 64 out-rows x 8 chunks
    int c = id>>3, r8 = id&7;
    union { unsigned short u[8]; uint4 v; } o;
    #pragma unroll
    for (int j=0;j<8;++j) o.u[j] = T[r8*8+j][c];
    *(uint4*)(O + (size_t)(n0+c)*512 + k0 + r8*8) = o.v;
  }
}

// ---------------------------------------------------------------------------
// Transpose Vp bf16 [B*NK][512] -> Vpt [B][512][NK] (d-major per batch).
// ---------------------------------------------------------------------------
__global__ __launch_bounds__(256) void mab_vt(
    const unsigned short* __restrict__ Vp, unsigned short* __restrict__ Vpt)
{
  __shared__ unsigned short T[64][72];
  const int r0 = blockIdx.x*64;   // k within batch
  const int c0 = blockIdx.y*64;   // d
  const int b  = blockIdx.z;
  const int tid = threadIdx.x;
  #pragma unroll
  for (int i=0;i<2;++i){
    int id = tid + i*256;          // 512 = 64 rows x 8 chunks(8 bf16)
    int r = id>>3, c8 = id&7;
    *(uint4*)&T[r][c8*8] = *(const uint4*)(Vp + (size_t)(b*NKx + r0+r)*512 + c0 + c8*8);
  }
  __syncthreads();
  #pragma unroll
  for (int i=0;i<2;++i){
    int id = tid + i*256;
    int c = id>>3, r8 = id&7;
    union { unsigned short u[8]; uint4 v; } o;
    #pragma unroll
    for (int j=0;j<8;++j) o.u[j] = T[r8*8+j][c];
    *(uint4*)(Vpt + ((size_t)(b*512) + c0 + c)*NKx + r0 + r8*8) = o.v;
  }
}

// ---------------------------------------------------------------------------
// QKV projection GEMM with fused f32->bf16 A conversion.
// C[z][M,512] = (A_z[M,512] @ Wt_z^T + bias_z) * sc_z,  A f32 row-major.
// 128x128 tile, BK=64, 4 waves. A reg-staged + cvt_pk + ds_write (XOR swz);
// B via global_load_lds. A-prefetch issued at compute start (hides HBM).
// ---------------------------------------------------------------------------
__global__ __launch_bounds__(256) void mab_gemm_proj(
    const float* __restrict__ Qf, const float* __restrict__ Kf,
    const unsigned short* __restrict__ Wt,
    const float* __restrict__ bq, const float* __restrict__ bk, const float* __restrict__ bv,
    unsigned short* __restrict__ Cb, float kscale)
{
  __shared__ unsigned short As[128][64];
  __shared__ unsigned short Bs[128][64];
  const int z = blockIdx.z;
  const float* A = (z==0) ? Qf : Kf;
  const unsigned short* W = Wt + (size_t)z*512*512;
  const float* bias = (z==0)?bq:((z==1)?bk:bv);
  const float sc = (z==1) ? kscale : 1.0f;
  const int m0 = blockIdx.y*128, n0 = blockIdx.x*128;
  const int tid = threadIdx.x, w = tid>>6, lane = tid&63, g = lane>>4, q16 = lane&15;
  const int wr = w>>1, wc = w&1;

  f32x4 acc[4][4];
  #pragma unroll
  for (int m=0;m<4;++m)
    #pragma unroll
    for (int n=0;n<4;++n) acc[m][n] = (f32x4){0.f,0.f,0.f,0.f};

  // prologue: load A tile k0=0 into regs (8 x float4 per thread)
  float4 areg[8];
  #pragma unroll
  for (int i=0;i<8;++i){
    int id = i*256 + tid, row = id>>4, qc = id&15;
    areg[i] = *(const float4*)(A + (size_t)(m0+row)*512 + qc*4);
  }

  for (int k0 = 0; k0 < 512; k0 += 64){
    __syncthreads();
    // write converted A tile; issue B gloads
    #pragma unroll
    for (int i=0;i<8;++i){
      int id = i*256 + tid, row = id>>4, qc = id&15;
      unsigned int lo = cvtpk_bf16(areg[i].x, areg[i].y);
      unsigned int hi = cvtpk_bf16(areg[i].z, areg[i].w);
      unsigned int* dst = (unsigned int*)((char*)&As[0][0] + row*128
                          + ((qc>>1) ^ (row&7))*16 + (qc&1)*8);
      dst[0] = lo; dst[1] = hi;
    }
    #pragma unroll
    for (int i=0;i<4;++i){
      int o   = (w*4 + i)*1024 + lane*16;
      int row = o >> 7;
      int c   = (o >> 4) & 7;
      int cs  = c ^ (row & 7);
      gload16(W + (size_t)(n0+row)*512 + k0 + cs*8, (char*)&Bs[0][0] + (w*4+i)*1024);
    }
    __syncthreads();
    // prefetch next A tile during compute
    if (k0 + 64 < 512){
      #pragma unroll
      for (int i=0;i<8;++i){
        int id = i*256 + tid, row = id>>4, qc = id&15;
        areg[i] = *(const float4*)(A + (size_t)(m0+row)*512 + (k0+64) + qc*4);
      }
    }
    #pragma unroll
    for (int ks=0;ks<2;++ks){
      bf16x8 af[4], bfr[4];
      #pragma unroll
      for (int m=0;m<4;++m){
        int row = wr*64 + m*16 + q16;
        int c   = (ks*4 + g) ^ (row & 7);
        af[m] = *(const bf16x8*)((const char*)&As[0][0] + row*128 + c*16);
      }
      #pragma unroll
      for (int n=0;n<4;++n){
        int row = wc*64 + n*16 + q16;
        int c   = (ks*4 + g) ^ (row & 7);
        bfr[n] = *(const bf16x8*)((const char*)&Bs[0][0] + row*128 + c*16);
      }
      #pragma unroll
      for (int m=0;m<4;++m)
        #pragma unroll
        for (int n=0;n<4;++n)
          acc[m][n] = __builtin_amdgcn_mfma_f32_16x16x32_bf16(af[m], bfr[n], acc[m][n], 0,0,0);
    }
  }

  const size_t ZS = (size_t)8192*512;
  #pragma unroll
  for (int m=0;m<4;++m){
    const int rowl = wr*64 + m*16 + g*4;
    #pragma unroll
    for (int n=0;n<4;++n){
      const int col = n0 + wc*64 + n*16 + q16;
      const float bv2 = bias[col];
      #pragma unroll
      for (int r=0;r<4;++r){
        float v = (acc[m][n][r] + bv2) * sc;
        Cb[(size_t)z*ZS + (size_t)(m0 + rowl + r)*512 + col] = f2bf(v);
      }
    }
  }
}

// ---------------------------------------------------------------------------
// bf16-A MFMA GEMM for the MLP: C = op(A @ W^T + bias) (+res)
// ---------------------------------------------------------------------------
__global__ __launch_bounds__(256) void mab_gemm_mfma(
    const unsigned short* __restrict__ A, const unsigned short* __restrict__ W,
    const float* __restrict__ bias, const float* __restrict__ res,
    unsigned short* __restrict__ Cb, float* __restrict__ Cf, int relu)
{
  __shared__ unsigned short As[128][64];
  __shared__ unsigned short Bs[128][64];
  const int m0 = blockIdx.y*128, n0 = blockIdx.x*128;
  const int tid = threadIdx.x, w = tid>>6, lane = tid&63, g = lane>>4, q16 = lane&15;
  const int wr = w>>1, wc = w&1;

  f32x4 acc[4][4];
  #pragma unroll
  for (int m=0;m<4;++m)
    #pragma unroll
    for (int n=0;n<4;++n) acc[m][n] = (f32x4){0.f,0.f,0.f,0.f};

  for (int k0 = 0; k0 < 512; k0 += 64){
    __syncthreads();
    #pragma unroll
    for (int i=0;i<4;++i){
      int o   = (w*4 + i)*1024 + lane*16;
      int row = o >> 7;
      int c   = (o >> 4) & 7;
      int cs  = c ^ (row & 7);
      gload16(A + (size_t)(m0+row)*512 + k0 + cs*8, (char*)&As[0][0] + (w*4+i)*1024);
      gload16(W + (size_t)(n0+row)*512 + k0 + cs*8, (char*)&Bs[0][0] + (w*4+i)*1024);
    }
    __syncthreads();
    #pragma unroll
    for (int ks=0;ks<2;++ks){
      bf16x8 af[4], bfr[4];
      #pragma unroll
      for (int m=0;m<4;++m){
        int row = wr*64 + m*16 + q16;
        int c   = (ks*4 + g) ^ (row & 7);
        af[m] = *(const bf16x8*)((const char*)&As[0][0] + row*128 + c*16);
      }
      #pragma unroll
      for (int n=0;n<4;++n){
        int row = wc*64 + n*16 + q16;
        int c   = (ks*4 + g) ^ (row & 7);
        bfr[n] = *(const bf16x8*)((const char*)&Bs[0][0] + row*128 + c*16);
      }
      #pragma unroll
      for (int m=0;m<4;++m)
        #pragma unroll
        for (int n=0;n<4;++n)
          acc[m][n] = __builtin_amdgcn_mfma_f32_16x16x32_bf16(af[m], bfr[n], acc[m][n], 0,0,0);
    }
  }

  #pragma unroll
  for (int m=0;m<4;++m){
    const int rowl = wr*64 + m*16 + g*4;
    #pragma unroll
    for (int n=0;n<4;++n){
      const int col = n0 + wc*64 + n*16 + q16;
      const float bv = bias[col];
      #pragma unroll
      for (int r=0;r<4;++r){
        float v = acc[m][n][r] + bv;
        if (relu) v = fmaxf(v, 0.f);
        size_t off = (size_t)(m0 + rowl + r)*512 + col;
        if (res) v += res[off];
        if (Cb) Cb[off] = f2bf(v);
        if (Cf) Cf[off] = v;
      }
    }
  }
}

// ---------------------------------------------------------------------------
// MFMA flash attention, 32x32 swapped-operand, exp2 domain.
// Grid (NQ/128, H, B), 4 waves x 32 q-rows. KVBLK=64, double-buffered K/V via
// global_load_lds + XOR swizzle; Kpos register ping-pong prefetch (1 tile
// ahead); P in registers (cvt_pk + permlane32_swap); defer-max (2^11.54=e^8).
// Kp pre-scaled by log2e/sqrt(512). Vpt is d-major [B][512][NK].
// X = Qh + O/l + (akp/l)*vp   (pre-LayerNorm), f32.
// ---------------------------------------------------------------------------
__global__ __launch_bounds__(256) void mab_attn2(
    const unsigned short* __restrict__ Qp, const unsigned short* __restrict__ Kp,
    const unsigned short* __restrict__ Vpt,
    const float* __restrict__ Kpos, const float* __restrict__ kp, const float* __restrict__ vp,
    float* __restrict__ X)
{
  __shared__ unsigned short Kb[2][64][64];   // [k'][d], swizzled chunks
  __shared__ unsigned short Vb[2][64][64];   // [d][k'], swizzled chunks
  __shared__ unsigned short Qs[128][72];     // [q][d], padded

  const int q0 = blockIdx.x*128;
  const int h  = blockIdx.y;
  const int b  = blockIdx.z;
  const int tid = threadIdx.x, w = tid>>6, lane = tid&63;
  const int q32 = lane & 31, hi = lane >> 5;

  const unsigned short* Qg = Qp + ((size_t)(b*NQx + q0))*Dx + h*64;
  const unsigned short* Kg = Kp + ((size_t)b*NKx)*Dx + h*64;
  const unsigned short* Vg = Vpt + ((size_t)(b*512) + h*64)*NKx;
  const float* KProw = Kpos + (size_t)b*NQx*NKx + (size_t)(q0 + w*32 + q32)*NKx;

  const int sr = lane>>3;        // staging row 0..7
  const int sc = lane&7;         // staging chunk 0..7

  // prologue: stage K/V tile 0, stage Q, load Kpos tile 0
  #pragma unroll
  for (int i=0;i<2;++i){
    int r  = i*8 + sr;
    int cs = sc ^ (r & 7);
    gload16(Kg + (size_t)(w*16 + r)*Dx + cs*8, (char*)&Kb[0][0][0] + w*2048 + i*1024);
    gload16(Vg + (size_t)(w*16 + r)*NKx + cs*8, (char*)&Vb[0][0][0] + w*2048 + i*1024);
  }
  f32x4 kqA[2][4], kqB[2][4];
  #pragma unroll
  for (int n=0;n<2;++n)
    #pragma unroll
    for (int a=0;a<4;++a)
      kqA[n][a] = *(const f32x4*)(KProw + n*32 + a*8 + hi*4);
  #pragma unroll
  for (int i=0;i<4;++i){
    int id = tid + i*256;
    int r = id>>3, c8 = id&7;
    *(uint4*)&Qs[r][c8*8] = *(const uint4*)(Qg + (size_t)r*Dx + c8*8);
  }
  __syncthreads();

  // hoist Q B-frags
  bf16x8 qf[4];
  #pragma unroll
  for (int ds=0; ds<4; ++ds)
    qf[ds] = *(const bf16x8*)&Qs[w*32 + q32][ds*16 + hi*8];

  // qkp = (Qh . kp) * log2e for own q-row
  float qkp = 0.f;
  #pragma unroll
  for (int ds=0; ds<4; ++ds){
    union { bf16x8 v; unsigned short u[8]; } qa; qa.v = qf[ds];
    #pragma unroll
    for (int j=0;j<8;++j)
      qkp = fmaf(bf2f(qa.u[j]), kp[ds*16 + hi*8 + j], qkp);
  }
  qkp += __shfl_xor(qkp, 32);
  qkp *= 1.4426950408889634f;

  float m_i = -1e30f, l_i = 0.f, a_i = 0.f;
  f32x16 accT[2];
  #pragma unroll
  for (int db=0; db<2; ++db)
    #pragma unroll
    for (int r=0;r<16;++r) accT[db][r] = 0.f;

  const int NT = NKx/64;

  auto tile_body = [&](int kt, f32x4 (&kqc)[2][4], f32x4 (&kqn)[2][4]) {
    const int cur = kt & 1;
    const int k0 = kt*64;
    // prefetch next tile: Kpos -> regs, K/V -> other LDS buffer
    if (kt+1 < NT){
      const int k1 = k0 + 64;
      #pragma unroll
      for (int n=0;n<2;++n)
        #pragma unroll
        for (int a=0;a<4;++a)
          kqn[n][a] = *(const f32x4*)(KProw + k1 + n*32 + a*8 + hi*4);
      #pragma unroll
      for (int i=0;i<2;++i){
        int r  = i*8 + sr;
        int cs = sc ^ (r & 7);
        gload16(Kg + (size_t)(k1 + w*16 + r)*Dx + cs*8,
                (char*)&Kb[cur^1][0][0] + w*2048 + i*1024);
        gload16(Vg + (size_t)(w*16 + r)*NKx + k1 + cs*8,
                (char*)&Vb[cur^1][0][0] + w*2048 + i*1024);
      }
    }
    __builtin_amdgcn_sched_barrier(0);

    // S^T = K . Q^T (log2 domain; Kp pre-scaled by log2e/sqrt(512))
    f32x16 sT[2];
    __builtin_amdgcn_s_setprio(1);
    #pragma unroll
    for (int n=0;n<2;++n){
      f32x16 c;
      #pragma unroll
      for (int r=0;r<16;++r) c[r] = 0.f;
      #pragma unroll
      for (int ds=0; ds<4; ++ds){
        int row = n*32 + q32;
        int cc  = (ds*2 + hi) ^ (q32 & 7);
        bf16x8 kf = *(const bf16x8*)((const char*)&Kb[cur][0][0] + row*128 + cc*16);
        c = __builtin_amdgcn_mfma_f32_32x32x16_bf16(kf, qf[ds], c, 0,0,0);
      }
      sT[n] = c;
    }
    __builtin_amdgcn_s_setprio(0);

    // + Kpos * qkp (log2 domain); k' = n*32 + (r&3) + 8*(r>>2) + 4*hi
    #pragma unroll
    for (int n=0;n<2;++n)
      #pragma unroll
      for (int r=0;r<16;++r)
        sT[n][r] = fmaf(kqc[n][r>>2][r&3], qkp, sT[n][r]);

    // tree max via v_max3
    float m0a = fmax3(sT[0][0], sT[0][1], sT[0][2]);
    float m0b = fmax3(sT[0][3], sT[0][4], sT[0][5]);
    float m0c = fmax3(sT[0][6], sT[0][7], sT[0][8]);
    float m0d = fmax3(sT[0][9], sT[0][10], sT[0][11]);
    float m0e = fmax3(sT[0][12], sT[0][13], sT[0][14]);
    float m1a = fmax3(sT[1][0], sT[1][1], sT[1][2]);
    float m1b = fmax3(sT[1][3], sT[1][4], sT[1][5]);
    float m1c = fmax3(sT[1][6], sT[1][7], sT[1][8]);
    float m1d = fmax3(sT[1][9], sT[1][10], sT[1][11]);
    float m1e = fmax3(sT[1][12], sT[1][13], sT[1][14]);
    float rm = fmax3(fmax3(m0a, m0b, m0c), fmax3(m0d, m0e, sT[0][15]),
                     fmax3(fmax3(m1a, m1b, m1c), fmax3(m1d, m1e, sT[1][15]), m_i));
    rm = fmaxf(rm, __shfl_xor(rm, 32));

    if (!__all(rm <= m_i + 11.544f)){      // 2^11.544 = e^8 bound
      float al = fexp2(m_i - rm);
      m_i = rm;
      l_i *= al; a_i *= al;
      #pragma unroll
      for (int db=0; db<2; ++db)
        #pragma unroll
        for (int r=0;r<16;++r) accT[db][r] *= al;
    }

    float ps = 0.f, pk = 0.f;
    #pragma unroll
    for (int n=0;n<2;++n)
      #pragma unroll
      for (int r=0;r<16;++r){
        float p = fexp2(sT[n][r] - m_i);
        sT[n][r] = p;
        ps += p;
        pk = fmaf(p, kqc[n][r>>2][r&3], pk);
      }
    ps += __shfl_xor(ps, 32);
    pk += __shfl_xor(pk, 32);
    l_i += ps; a_i += pk;

    // pack P to bf16 A-frags in-register
    union PW { unsigned int u[4]; bf16x8 v; } pa[4];
    #pragma unroll
    for (int n=0;n<2;++n){
      unsigned int w0 = cvtpk_bf16(sT[n][0],  sT[n][1]);
      unsigned int w1 = cvtpk_bf16(sT[n][2],  sT[n][3]);
      unsigned int w2 = cvtpk_bf16(sT[n][4],  sT[n][5]);
      unsigned int w3 = cvtpk_bf16(sT[n][6],  sT[n][7]);
      unsigned int w4 = cvtpk_bf16(sT[n][8],  sT[n][9]);
      unsigned int w5 = cvtpk_bf16(sT[n][10], sT[n][11]);
      unsigned int w6 = cvtpk_bf16(sT[n][12], sT[n][13]);
      unsigned int w7 = cvtpk_bf16(sT[n][14], sT[n][15]);
      plane32_swap(w0, w2);
      plane32_swap(w1, w3);
      plane32_swap(w4, w6);
      plane32_swap(w5, w7);
      pa[n*2+0].u[0]=w0; pa[n*2+0].u[1]=w1; pa[n*2+0].u[2]=w2; pa[n*2+0].u[3]=w3;
      pa[n*2+1].u[0]=w4; pa[n*2+1].u[1]=w5; pa[n*2+1].u[2]=w6; pa[n*2+1].u[3]=w7;
    }

    // O^T += V . P
    __builtin_amdgcn_s_setprio(1);
    #pragma unroll
    for (int st=0; st<4; ++st){
      #pragma unroll
      for (int db=0; db<2; ++db){
        int row = db*32 + q32;
        int cc  = (st*2 + hi) ^ (q32 & 7);
        bf16x8 vf = *(const bf16x8*)((const char*)&Vb[cur][0][0] + row*128 + cc*16);
        accT[db] = __builtin_amdgcn_mfma_f32_32x32x16_bf16(vf, pa[st].v, accT[db], 0,0,0);
      }
    }
    __builtin_amdgcn_s_setprio(0);

    __syncthreads();
  };

  for (int kt = 0; kt < NT; kt += 2){
    tile_body(kt,   kqA, kqB);
    tile_body(kt+1, kqB, kqA);
  }

  // epilogue: X = Qh + O/l + (akp/l)*vp ; d = db*32 + 8a + 4hi + c
  float inv = 1.0f / l_i;
  float aw  = a_i * inv;
  float* Xrow = X + ((size_t)(b*NQx + q0 + w*32 + q32))*Dx + h*64;
  #pragma unroll
  for (int db=0; db<2; ++db){
    #pragma unroll
    for (int a=0; a<4; ++a){
      int d0 = db*32 + a*8 + hi*4;
      f32x4 vpv = *(const f32x4*)(vp + d0);
      float4 o;
      o.x = fmaf(accT[db][a*4+0], inv, bf2f(Qs[w*32+q32][d0+0]) + aw*vpv[0]);
      o.y = fmaf(accT[db][a*4+1], inv, bf2f(Qs[w*32+q32][d0+1]) + aw*vpv[1]);
      o.z = fmaf(accT[db][a*4+2], inv, bf2f(Qs[w*32+q32][d0+2]) + aw*vpv[2]);
      o.w = fmaf(accT[db][a*4+3], inv, bf2f(Qs[w*32+q32][d0+3]) + aw*vpv[3]);
      *(float4*)(Xrow + d0) = o;
    }
  }
}

// ---------------------------------------------------------------------------
// Row LayerNorm over 512; optional secondary bf16 output.
// ---------------------------------------------------------------------------
__global__ __launch_bounds__(256) void mab_ln2(
    const float* __restrict__ Xin, const float* __restrict__ g,
    const float* __restrict__ be, float* __restrict__ Yf, unsigned short* __restrict__ Yb)
{
  const int row = blockIdx.x;
  const int tid = threadIdx.x;
  const float* x = Xin + (size_t)row*Dx;
  float2 v = *(const float2*)(x + tid*2);
  float s  = v.x + v.y;
  float sq = fmaf(v.x,v.x, v.y*v.y);
  #pragma unroll
  for (int m=1; m<64; m<<=1){ s += __shfl_xor(s,m); sq += __shfl_xor(sq,m); }
  __shared__ float red[2][4];
  const int wid = tid>>6, lane = tid&63;
  if (lane==0){ red[0][wid]=s; red[1][wid]=sq; }
  __syncthreads();
  s  = red[0][0]+red[0][1]+red[0][2]+red[0][3];
  sq = red[1][0]+red[1][1]+red[1][2]+red[1][3];
  float mean = s*(1.0f/Dx);
  float var  = sq*(1.0f/Dx) - mean*mean;
  float rstd = rsqrtf(var + 1e-5f);
  float2 gg = *(const float2*)(g  + tid*2);
  float2 bb = *(const float2*)(be + tid*2);
  float2 o;
  o.x = (v.x-mean)*rstd*gg.x + bb.x;
  o.y = (v.y-mean)*rstd*gg.y + bb.y;
  if (Yf) *(float2*)(Yf + (size_t)row*Dx + tid*2) = o;
  if (Yb){
    ushort2 ob; ob.x = f2bf(o.x); ob.y = f2bf(o.y);
    *(ushort2*)(Yb + (size_t)row*Dx + tid*2) = ob;
  }
}

// ---------------------------------------------------------------------------
extern "C" void kernel_launch(void* const* d_in, const int* in_sizes, int n_in,
                              void* d_out, int out_size, void* d_ws, size_t ws_size,
                              hipStream_t stream)
{
  const float* Q    = (const float*)d_in[0];
  const float* K    = (const float*)d_in[1];
  const float* Kpos = (const float*)d_in[2];
  const float* Wq   = (const float*)d_in[3];
  const float* bq   = (const float*)d_in[4];
  const float* Wk   = (const float*)d_in[5];
  const float* bk   = (const float*)d_in[6];
  const float* Wv   = (const float*)d_in[7];
  const float* bv   = (const float*)d_in[8];
  const float* kp   = (const float*)d_in[9];
  const float* vp   = (const float*)d_in[10];
  const float* W0   = (const float*)d_in[11];
  const float* b0   = (const float*)d_in[12];
  const float* W1   = (const float*)d_in[13];
  const float* b1   = (const float*)d_in[14];
  const float* g0   = (const float*)d_in[15];
  const float* be0  = (const float*)d_in[16];
  const float* g1   = (const float*)d_in[17];
  const float* be1  = (const float*)d_in[18];
  float* out = (float*)d_out;
  char* wsb  = (char*)d_ws;

  const size_t MB = 1024*1024;
  unsigned short* Qp  = (unsigned short*)(wsb);          // 8 MiB bf16 [8192][512]
  unsigned short* Kp  = (unsigned short*)(wsb + 8*MB);   // pre-scaled (log2e/sqrt512)
  unsigned short* Vp  = (unsigned short*)(wsb + 16*MB);
  float*          O0  = (float*)         (wsb + 24*MB);  // 16 MiB f32
  unsigned short* Vpt = (unsigned short*)(wsb + 40*MB);  // 8 MiB
  unsigned short* O0b = (unsigned short*)(wsb + 48*MB);  // 8 MiB
  unsigned short* Wt  = (unsigned short*)(wsb + 56*MB);  // 2.5 MiB [5][512][512]
  unsigned short* T1  = Vp;                              // reuse after vt

  const float kscale = 0.044194173824159216f * 1.4426950408889634f; // log2e/sqrt(512)

  // weight transposes (Wq,Wk,Wv,W0,W1)
  mab_wt<<<dim3(8,8,5), 256, 0, stream>>>(Wq, Wk, Wv, W0, W1, Wt);
  // fused Q/K/V projections from f32 inputs (z=0,1,2)
  mab_gemm_proj<<<dim3(4,64,3), 256, 0, stream>>>(Q, K, Wt, bq, bk, bv, Qp, kscale);
  // V transpose to d-major
  mab_vt<<<dim3(32,8,4), 256, 0, stream>>>(Vp, Vpt);
  // fused attention (32x32 swapped structure, exp2 domain)
  mab_attn2<<<dim3(16,8,4), 256, 0, stream>>>(Qp, Kp, Vpt, Kpos, kp, vp, out);
  // LN0 -> O0 (f32) + O0b (bf16)
  mab_ln2<<<8192, 256, 0, stream>>>(out, g0, be0, O0, O0b);
  // T1 = relu(O0 @ W0 + b0)  (bf16 out)
  mab_gemm_mfma<<<dim3(4,64,1), 256, 0, stream>>>(
      O0b, Wt + (size_t)3*512*512, b0, nullptr, T1, nullptr, 1);
  // out = O0 + relu(T1 @ W1 + b1)  (f32 out)
  mab_gemm_mfma<<<dim3(4,64,1), 256, 0, stream>>>(
      T1, Wt + (size_t)4*512*512, b1, O0, nullptr, out, 1);
  // final LN in-place
  mab_ln2<<<8192, 256, 0, stream>>>(out, g1, be1, out, nullptr);
}

// Round 5
// 210.026 us; speedup vs baseline: 1.1646x; 1.1646x over previous
//
#include <hip/hip_runtime.h>
#include <math.h>

// Problem constants (MAB_50921132261692)
#define Bx  4
#define NQx 2048
#define NKx 2048
#define Dx  512
#define Hx  8

typedef __attribute__((ext_vector_type(8))) __bf16 bf16x8;
typedef __attribute__((ext_vector_type(4))) float f32x4;
typedef __attribute__((ext_vector_type(16))) float f32x16;

typedef const __attribute__((address_space(1))) unsigned int* gas_ptr;
typedef __attribute__((address_space(3))) unsigned int* lds_ptr;

__device__ __forceinline__ void gload16(const void* g, void* l){
  __builtin_amdgcn_global_load_lds((gas_ptr)g, (lds_ptr)l, 16, 0, 0);
}

__device__ __forceinline__ unsigned short f2bf(float f){
  union { float f; unsigned int u; } v; v.f = f;
  unsigned int r = (v.u + 0x7FFFu + ((v.u >> 16) & 1u)) >> 16;
  return (unsigned short)r;
}
__device__ __forceinline__ float bf2f(unsigned short u){
  union { unsigned int u; float f; } v; v.u = ((unsigned int)u) << 16; return v.f;
}
__device__ __forceinline__ unsigned int cvtpk_bf16(float a, float b){
  unsigned int d;
  asm("v_cvt_pk_bf16_f32 %0, %1, %2" : "=v"(d) : "v"(a), "v"(b));
  return d;
}
__device__ __forceinline__ void plane32_swap(unsigned int& a, unsigned int& b){
  asm("v_permlane32_swap_b32 %0, %1" : "+v"(a), "+v"(b));
}
__device__ __forceinline__ float fexp2(float x){           // D = 2^x
  float d; asm("v_exp_f32 %0, %1" : "=v"(d) : "v"(x)); return d;
}
__device__ __forceinline__ float fmax3(float a, float b, float c){
  float d; asm("v_max3_f32 %0, %1, %2, %3" : "=v"(d) : "v"(a), "v"(b), "v"(c)); return d;
}

// ---------------------------------------------------------------------------
// Transpose + convert 5 weights [512][512] f32 -> Wt bf16 [z][N=512][K=512].
// ---------------------------------------------------------------------------
__global__ __launch_bounds__(256) void mab_wt(
    const float* __restrict__ Wq, const float* __restrict__ Wk, const float* __restrict__ Wv,
    const float* __restrict__ W0, const float* __restrict__ W1,
    unsigned short* __restrict__ Wt)
{
  __shared__ unsigned short T[64][72];
  const int z = blockIdx.z;
  const float* W = (z==0)?Wq:(z==1)?Wk:(z==2)?Wv:(z==3)?W0:W1;
  unsigned short* O = Wt + (size_t)z*512*512;
  const int k0 = blockIdx.x*64, n0 = blockIdx.y*64;
  const int tid = threadIdx.x;
  #pragma unroll
  for (int i=0;i<4;++i){
    int id = tid + i*256;          // 1024 = 64 rows x 16 float4
    int r = id>>4, c4 = id&15;
    float4 v = *(const float4*)(W + (size_t)(k0+r)*512 + n0 + c4*4);
    ushort4 o; o.x=f2bf(v.x); o.y=f2bf(v.y); o.z=f2bf(v.z); o.w=f2bf(v.w);
    *(ushort4*)&T[r][c4*4] = o;
  }
  __syncthreads();
  #pragma unroll
  for (int i=0;i<2;++i){
    int id = tid + i*256;          // 512 = 64 out-rows x 8 chunks
    int c = id>>3, r8 = id&7;
    union { unsigned short u[8]; uint4 v; } o;
    #pragma unroll
    for (int j=0;j<8;++j) o.u[j] = T[r8*8+j][c];
    *(uint4*)(O + (size_t)(n0+c)*512 + k0 + r8*8) = o.v;
  }
}

// ---------------------------------------------------------------------------
// Transpose Vp bf16 [B*NK][512] -> Vpt [B][512][NK] (d-major per batch).
// ---------------------------------------------------------------------------
__global__ __launch_bounds__(256) void mab_vt(
    const unsigned short* __restrict__ Vp, unsigned short* __restrict__ Vpt)
{
  __shared__ unsigned short T[64][72];
  const int r0 = blockIdx.x*64;   // k within batch
  const int c0 = blockIdx.y*64;   // d
  const int b  = blockIdx.z;
  const int tid = threadIdx.x;
  #pragma unroll
  for (int i=0;i<2;++i){
    int id = tid + i*256;          // 512 = 64 rows x 8 chunks(8 bf16)
    int r = id>>3, c8 = id&7;
    *(uint4*)&T[r][c8*8] = *(const uint4*)(Vp + (size_t)(b*NKx + r0+r)*512 + c0 + c8*8);
  }
  __syncthreads();
  #pragma unroll
  for (int i=0;i<2;++i){
    int id = tid + i*256;
    int c = id>>3, r8 = id&7;
    union { unsigned short u[8]; uint4 v; } o;
    #pragma unroll
    for (int j=0;j<8;++j) o.u[j] = T[r8*8+j][c];
    *(uint4*)(Vpt + ((size_t)(b*512) + c0 + c)*NKx + r0 + r8*8) = o.v;
  }
}

// ---------------------------------------------------------------------------
// QKV projection GEMM with fused f32->bf16 A conversion.
// C[z][M,512] = (A_z[M,512] @ Wt_z^T + bias_z) * sc_z,  A f32 row-major.
// 128x128 tile, BK=64, 4 waves. A reg-staged + cvt_pk + ds_write (XOR swz);
// B via global_load_lds. A-prefetch issued at compute start (hides HBM).
// ---------------------------------------------------------------------------
__global__ __launch_bounds__(256) void mab_gemm_proj(
    const float* __restrict__ Qf, const float* __restrict__ Kf,
    const unsigned short* __restrict__ Wt,
    const float* __restrict__ bq, const float* __restrict__ bk, const float* __restrict__ bv,
    unsigned short* __restrict__ Cb, float kscale)
{
  __shared__ unsigned short As[128][64];
  __shared__ unsigned short Bs[128][64];
  const int z = blockIdx.z;
  const float* A = (z==0) ? Qf : Kf;
  const unsigned short* W = Wt + (size_t)z*512*512;
  const float* bias = (z==0)?bq:((z==1)?bk:bv);
  const float sc = (z==1) ? kscale : 1.0f;
  const int m0 = blockIdx.y*128, n0 = blockIdx.x*128;
  const int tid = threadIdx.x, w = tid>>6, lane = tid&63, g = lane>>4, q16 = lane&15;
  const int wr = w>>1, wc = w&1;

  f32x4 acc[4][4];
  #pragma unroll
  for (int m=0;m<4;++m)
    #pragma unroll
    for (int n=0;n<4;++n) acc[m][n] = (f32x4){0.f,0.f,0.f,0.f};

  // prologue: load A tile k0=0 into regs (8 x float4 per thread)
  float4 areg[8];
  #pragma unroll
  for (int i=0;i<8;++i){
    int id = i*256 + tid, row = id>>4, qc = id&15;
    areg[i] = *(const float4*)(A + (size_t)(m0+row)*512 + qc*4);
  }

  for (int k0 = 0; k0 < 512; k0 += 64){
    __syncthreads();
    // write converted A tile; issue B gloads
    #pragma unroll
    for (int i=0;i<8;++i){
      int id = i*256 + tid, row = id>>4, qc = id&15;
      unsigned int lo = cvtpk_bf16(areg[i].x, areg[i].y);
      unsigned int hi = cvtpk_bf16(areg[i].z, areg[i].w);
      unsigned int* dst = (unsigned int*)((char*)&As[0][0] + row*128
                          + ((qc>>1) ^ (row&7))*16 + (qc&1)*8);
      dst[0] = lo; dst[1] = hi;
    }
    #pragma unroll
    for (int i=0;i<4;++i){
      int o   = (w*4 + i)*1024 + lane*16;
      int row = o >> 7;
      int c   = (o >> 4) & 7;
      int cs  = c ^ (row & 7);
      gload16(W + (size_t)(n0+row)*512 + k0 + cs*8, (char*)&Bs[0][0] + (w*4+i)*1024);
    }
    __syncthreads();
    // prefetch next A tile during compute
    if (k0 + 64 < 512){
      #pragma unroll
      for (int i=0;i<8;++i){
        int id = i*256 + tid, row = id>>4, qc = id&15;
        areg[i] = *(const float4*)(A + (size_t)(m0+row)*512 + (k0+64) + qc*4);
      }
    }
    #pragma unroll
    for (int ks=0;ks<2;++ks){
      bf16x8 af[4], bfr[4];
      #pragma unroll
      for (int m=0;m<4;++m){
        int row = wr*64 + m*16 + q16;
        int c   = (ks*4 + g) ^ (row & 7);
        af[m] = *(const bf16x8*)((const char*)&As[0][0] + row*128 + c*16);
      }
      #pragma unroll
      for (int n=0;n<4;++n){
        int row = wc*64 + n*16 + q16;
        int c   = (ks*4 + g) ^ (row & 7);
        bfr[n] = *(const bf16x8*)((const char*)&Bs[0][0] + row*128 + c*16);
      }
      #pragma unroll
      for (int m=0;m<4;++m)
        #pragma unroll
        for (int n=0;n<4;++n)
          acc[m][n] = __builtin_amdgcn_mfma_f32_16x16x32_bf16(af[m], bfr[n], acc[m][n], 0,0,0);
    }
  }

  const size_t ZS = (size_t)8192*512;
  #pragma unroll
  for (int m=0;m<4;++m){
    const int rowl = wr*64 + m*16 + g*4;
    #pragma unroll
    for (int n=0;n<4;++n){
      const int col = n0 + wc*64 + n*16 + q16;
      const float bv2 = bias[col];
      #pragma unroll
      for (int r=0;r<4;++r){
        float v = (acc[m][n][r] + bv2) * sc;
        Cb[(size_t)z*ZS + (size_t)(m0 + rowl + r)*512 + col] = f2bf(v);
      }
    }
  }
}

// ---------------------------------------------------------------------------
// bf16-A MFMA GEMM for the MLP: C = op(A @ W^T + bias) (+res)
// ---------------------------------------------------------------------------
__global__ __launch_bounds__(256) void mab_gemm_mfma(
    const unsigned short* __restrict__ A, const unsigned short* __restrict__ W,
    const float* __restrict__ bias, const float* __restrict__ res,
    unsigned short* __restrict__ Cb, float* __restrict__ Cf, int relu)
{
  __shared__ unsigned short As[128][64];
  __shared__ unsigned short Bs[128][64];
  const int m0 = blockIdx.y*128, n0 = blockIdx.x*128;
  const int tid = threadIdx.x, w = tid>>6, lane = tid&63, g = lane>>4, q16 = lane&15;
  const int wr = w>>1, wc = w&1;

  f32x4 acc[4][4];
  #pragma unroll
  for (int m=0;m<4;++m)
    #pragma unroll
    for (int n=0;n<4;++n) acc[m][n] = (f32x4){0.f,0.f,0.f,0.f};

  for (int k0 = 0; k0 < 512; k0 += 64){
    __syncthreads();
    #pragma unroll
    for (int i=0;i<4;++i){
      int o   = (w*4 + i)*1024 + lane*16;
      int row = o >> 7;
      int c   = (o >> 4) & 7;
      int cs  = c ^ (row & 7);
      gload16(A + (size_t)(m0+row)*512 + k0 + cs*8, (char*)&As[0][0] + (w*4+i)*1024);
      gload16(W + (size_t)(n0+row)*512 + k0 + cs*8, (char*)&Bs[0][0] + (w*4+i)*1024);
    }
    __syncthreads();
    #pragma unroll
    for (int ks=0;ks<2;++ks){
      bf16x8 af[4], bfr[4];
      #pragma unroll
      for (int m=0;m<4;++m){
        int row = wr*64 + m*16 + q16;
        int c   = (ks*4 + g) ^ (row & 7);
        af[m] = *(const bf16x8*)((const char*)&As[0][0] + row*128 + c*16);
      }
      #pragma unroll
      for (int n=0;n<4;++n){
        int row = wc*64 + n*16 + q16;
        int c   = (ks*4 + g) ^ (row & 7);
        bfr[n] = *(const bf16x8*)((const char*)&Bs[0][0] + row*128 + c*16);
      }
      #pragma unroll
      for (int m=0;m<4;++m)
        #pragma unroll
        for (int n=0;n<4;++n)
          acc[m][n] = __builtin_amdgcn_mfma_f32_16x16x32_bf16(af[m], bfr[n], acc[m][n], 0,0,0);
    }
  }

  #pragma unroll
  for (int m=0;m<4;++m){
    const int rowl = wr*64 + m*16 + g*4;
    #pragma unroll
    for (int n=0;n<4;++n){
      const int col = n0 + wc*64 + n*16 + q16;
      const float bv = bias[col];
      #pragma unroll
      for (int r=0;r<4;++r){
        float v = acc[m][n][r] + bv;
        if (relu) v = fmaxf(v, 0.f);
        size_t off = (size_t)(m0 + rowl + r)*512 + col;
        if (res) v += res[off];
        if (Cb) Cb[off] = f2bf(v);
        if (Cf) Cf[off] = v;
      }
    }
  }
}

// ---------------------------------------------------------------------------
// MFMA flash attention, 32x32 swapped-operand, exp2 domain.
// Grid (NQ/128, H, B), 4 waves x 32 q-rows. KVBLK=64, double-buffered K/V via
// global_load_lds + XOR swizzle. Kpos reload-in-place prefetch: kq consumed
// in bias-fma/pk, then the SAME registers are reloaded with tile kt+1's
// Kpos (WAR keeps order; PV + barrier + next QK^T cover the L3 latency).
// End-of-tile barrier is counted: s_waitcnt vmcnt(8) retires the 4 K/V
// gloads while leaving the 8 kq loads in flight (no vmcnt(0) drain).
// P in registers (cvt_pk + permlane32_swap); defer-max (2^11.544 = e^8).
// Kp pre-scaled by log2e/sqrt(512). Vpt is d-major [B][512][NK].
// X = Qh + O/l + (akp/l)*vp   (pre-LayerNorm), f32.
// ---------------------------------------------------------------------------
__global__ __launch_bounds__(256) void mab_attn2(
    const unsigned short* __restrict__ Qp, const unsigned short* __restrict__ Kp,
    const unsigned short* __restrict__ Vpt,
    const float* __restrict__ Kpos, const float* __restrict__ kp, const float* __restrict__ vp,
    float* __restrict__ X)
{
  __shared__ unsigned short Kb[2][64][64];   // [k'][d], swizzled chunks
  __shared__ unsigned short Vb[2][64][64];   // [d][k'], swizzled chunks
  __shared__ unsigned short Qs[128][72];     // [q][d], padded

  const int q0 = blockIdx.x*128;
  const int h  = blockIdx.y;
  const int b  = blockIdx.z;
  const int tid = threadIdx.x, w = tid>>6, lane = tid&63;
  const int q32 = lane & 31, hi = lane >> 5;

  const unsigned short* Qg = Qp + ((size_t)(b*NQx + q0))*Dx + h*64;
  const unsigned short* Kg = Kp + ((size_t)b*NKx)*Dx + h*64;
  const unsigned short* Vg = Vpt + ((size_t)(b*512) + h*64)*NKx;
  const float* KProw = Kpos + (size_t)b*NQx*NKx + (size_t)(q0 + w*32 + q32)*NKx;

  const int sr = lane>>3;        // staging row 0..7
  const int sc = lane&7;         // staging chunk 0..7

  // prologue: stage K/V tile 0, load Kpos tile 0, stage Q
  #pragma unroll
  for (int i=0;i<2;++i){
    int r  = i*8 + sr;
    int cs = sc ^ (r & 7);
    gload16(Kg + (size_t)(w*16 + r)*Dx + cs*8, (char*)&Kb[0][0][0] + w*2048 + i*1024);
    gload16(Vg + (size_t)(w*16 + r)*NKx + cs*8, (char*)&Vb[0][0][0] + w*2048 + i*1024);
  }
  f32x4 kq[2][4];
  #pragma unroll
  for (int n=0;n<2;++n)
    #pragma unroll
    for (int a=0;a<4;++a)
      kq[n][a] = *(const f32x4*)(KProw + n*32 + a*8 + hi*4);
  #pragma unroll
  for (int i=0;i<4;++i){
    int id = tid + i*256;
    int r = id>>3, c8 = id&7;
    *(uint4*)&Qs[r][c8*8] = *(const uint4*)(Qg + (size_t)r*Dx + c8*8);
  }
  __syncthreads();   // full drain once (prologue only)

  // hoist Q B-frags
  bf16x8 qf[4];
  #pragma unroll
  for (int ds=0; ds<4; ++ds)
    qf[ds] = *(const bf16x8*)&Qs[w*32 + q32][ds*16 + hi*8];

  // qkp = (Qh . kp) * log2e for own q-row
  float qkp = 0.f;
  #pragma unroll
  for (int ds=0; ds<4; ++ds){
    union { bf16x8 v; unsigned short u[8]; } qa; qa.v = qf[ds];
    #pragma unroll
    for (int j=0;j<8;++j)
      qkp = fmaf(bf2f(qa.u[j]), kp[ds*16 + hi*8 + j], qkp);
  }
  qkp += __shfl_xor(qkp, 32);
  qkp *= 1.4426950408889634f;

  float m_i = -1e30f, l_i = 0.f, a_i = 0.f;
  f32x16 accT[2];
  #pragma unroll
  for (int db=0; db<2; ++db)
    #pragma unroll
    for (int r=0;r<16;++r) accT[db][r] = 0.f;

  const int NT = NKx/64;

  for (int kt = 0; kt < NT; ++kt){
    const int cur = kt & 1;
    const int k0 = kt*64;

    // issue next K/V tile gloads (oldest in vmcnt FIFO this iteration)
    if (kt+1 < NT){
      const int k1 = k0 + 64;
      #pragma unroll
      for (int i=0;i<2;++i){
        int r  = i*8 + sr;
        int cs = sc ^ (r & 7);
        gload16(Kg + (size_t)(k1 + w*16 + r)*Dx + cs*8,
                (char*)&Kb[cur^1][0][0] + w*2048 + i*1024);
        gload16(Vg + (size_t)(w*16 + r)*NKx + k1 + cs*8,
                (char*)&Vb[cur^1][0][0] + w*2048 + i*1024);
      }
    }
    __builtin_amdgcn_sched_barrier(0);

    // S^T = K . Q^T (log2 domain; Kp pre-scaled by log2e/sqrt(512))
    f32x16 sT[2];
    __builtin_amdgcn_s_setprio(1);
    #pragma unroll
    for (int n=0;n<2;++n){
      f32x16 c;
      #pragma unroll
      for (int r=0;r<16;++r) c[r] = 0.f;
      #pragma unroll
      for (int ds=0; ds<4; ++ds){
        int row = n*32 + q32;
        int cc  = (ds*2 + hi) ^ (q32 & 7);
        bf16x8 kf = *(const bf16x8*)((const char*)&Kb[cur][0][0] + row*128 + cc*16);
        c = __builtin_amdgcn_mfma_f32_32x32x16_bf16(kf, qf[ds], c, 0,0,0);
      }
      sT[n] = c;
    }
    __builtin_amdgcn_s_setprio(0);

    // + Kpos * qkp (log2 domain); k' = n*32 + (r&3) + 8*(r>>2) + 4*hi
    #pragma unroll
    for (int n=0;n<2;++n)
      #pragma unroll
      for (int r=0;r<16;++r)
        sT[n][r] = fmaf(kq[n][r>>2][r&3], qkp, sT[n][r]);

    // tree max via v_max3
    float m0a = fmax3(sT[0][0], sT[0][1], sT[0][2]);
    float m0b = fmax3(sT[0][3], sT[0][4], sT[0][5]);
    float m0c = fmax3(sT[0][6], sT[0][7], sT[0][8]);
    float m0d = fmax3(sT[0][9], sT[0][10], sT[0][11]);
    float m0e = fmax3(sT[0][12], sT[0][13], sT[0][14]);
    float m1a = fmax3(sT[1][0], sT[1][1], sT[1][2]);
    float m1b = fmax3(sT[1][3], sT[1][4], sT[1][5]);
    float m1c = fmax3(sT[1][6], sT[1][7], sT[1][8]);
    float m1d = fmax3(sT[1][9], sT[1][10], sT[1][11]);
    float m1e = fmax3(sT[1][12], sT[1][13], sT[1][14]);
    float rm = fmax3(fmax3(m0a, m0b, m0c), fmax3(m0d, m0e, sT[0][15]),
                     fmax3(fmax3(m1a, m1b, m1c), fmax3(m1d, m1e, sT[1][15]), m_i));
    rm = fmaxf(rm, __shfl_xor(rm, 32));

    if (!__all(rm <= m_i + 11.544f)){      // 2^11.544 = e^8 bound
      float al = fexp2(m_i - rm);
      m_i = rm;
      l_i *= al; a_i *= al;
      #pragma unroll
      for (int db=0; db<2; ++db)
        #pragma unroll
        for (int r=0;r<16;++r) accT[db][r] *= al;
    }

    // exp + row-sum + Kpos-weighted sum (last use of kq)
    float ps = 0.f, pk = 0.f;
    #pragma unroll
    for (int n=0;n<2;++n)
      #pragma unroll
      for (int r=0;r<16;++r){
        float p = fexp2(sT[n][r] - m_i);
        sT[n][r] = p;
        ps += p;
        pk = fmaf(p, kq[n][r>>2][r&3], pk);
      }

    // reload kq in place with NEXT tile's Kpos (WAR enforces ordering;
    // consumed only after next tile's QK^T -> PV+barrier+QK^T cover latency)
    {
      const int kn = (kt+1 < NT) ? (k0 + 64) : k0;
      #pragma unroll
      for (int n=0;n<2;++n)
        #pragma unroll
        for (int a=0;a<4;++a)
          kq[n][a] = *(const f32x4*)(KProw + kn + n*32 + a*8 + hi*4);
    }

    ps += __shfl_xor(ps, 32);
    pk += __shfl_xor(pk, 32);
    l_i += ps; a_i += pk;

    // pack P to bf16 A-frags in-register
    union PW { unsigned int u[4]; bf16x8 v; } pa[4];
    #pragma unroll
    for (int n=0;n<2;++n){
      unsigned int w0 = cvtpk_bf16(sT[n][0],  sT[n][1]);
      unsigned int w1 = cvtpk_bf16(sT[n][2],  sT[n][3]);
      unsigned int w2 = cvtpk_bf16(sT[n][4],  sT[n][5]);
      unsigned int w3 = cvtpk_bf16(sT[n][6],  sT[n][7]);
      unsigned int w4 = cvtpk_bf16(sT[n][8],  sT[n][9]);
      unsigned int w5 = cvtpk_bf16(sT[n][10], sT[n][11]);
      unsigned int w6 = cvtpk_bf16(sT[n][12], sT[n][13]);
      unsigned int w7 = cvtpk_bf16(sT[n][14], sT[n][15]);
      plane32_swap(w0, w2);
      plane32_swap(w1, w3);
      plane32_swap(w4, w6);
      plane32_swap(w5, w7);
      pa[n*2+0].u[0]=w0; pa[n*2+0].u[1]=w1; pa[n*2+0].u[2]=w2; pa[n*2+0].u[3]=w3;
      pa[n*2+1].u[0]=w4; pa[n*2+1].u[1]=w5; pa[n*2+1].u[2]=w6; pa[n*2+1].u[3]=w7;
    }

    // O^T += V . P
    __builtin_amdgcn_s_setprio(1);
    #pragma unroll
    for (int st=0; st<4; ++st){
      #pragma unroll
      for (int db=0; db<2; ++db){
        int row = db*32 + q32;
        int cc  = (st*2 + hi) ^ (q32 & 7);
        bf16x8 vf = *(const bf16x8*)((const char*)&Vb[cur][0][0] + row*128 + cc*16);
        accT[db] = __builtin_amdgcn_mfma_f32_32x32x16_bf16(vf, pa[st].v, accT[db], 0,0,0);
      }
    }
    __builtin_amdgcn_s_setprio(0);

    // counted barrier: retire the 4 K/V gloads (oldest), keep 8 kq loads
    // in flight across the barrier.
    asm volatile("s_waitcnt vmcnt(8)" ::: "memory");
    __builtin_amdgcn_s_barrier();
  }

  // epilogue: X = Qh + O/l + (akp/l)*vp ; d = db*32 + 8a + 4hi + c
  float inv = 1.0f / l_i;
  float aw  = a_i * inv;
  float* Xrow = X + ((size_t)(b*NQx + q0 + w*32 + q32))*Dx + h*64;
  #pragma unroll
  for (int db=0; db<2; ++db){
    #pragma unroll
    for (int a=0; a<4; ++a){
      int d0 = db*32 + a*8 + hi*4;
      f32x4 vpv = *(const f32x4*)(vp + d0);
      float4 o;
      o.x = fmaf(accT[db][a*4+0], inv, bf2f(Qs[w*32+q32][d0+0]) + aw*vpv[0]);
      o.y = fmaf(accT[db][a*4+1], inv, bf2f(Qs[w*32+q32][d0+1]) + aw*vpv[1]);
      o.z = fmaf(accT[db][a*4+2], inv, bf2f(Qs[w*32+q32][d0+2]) + aw*vpv[2]);
      o.w = fmaf(accT[db][a*4+3], inv, bf2f(Qs[w*32+q32][d0+3]) + aw*vpv[3]);
      *(float4*)(Xrow + d0) = o;
    }
  }
}

// ---------------------------------------------------------------------------
// Row LayerNorm over 512; optional secondary bf16 output.
// ---------------------------------------------------------------------------
__global__ __launch_bounds__(256) void mab_ln2(
    const float* __restrict__ Xin, const float* __restrict__ g,
    const float* __restrict__ be, float* __restrict__ Yf, unsigned short* __restrict__ Yb)
{
  const int row = blockIdx.x;
  const int tid = threadIdx.x;
  const float* x = Xin + (size_t)row*Dx;
  float2 v = *(const float2*)(x + tid*2);
  float s  = v.x + v.y;
  float sq = fmaf(v.x,v.x, v.y*v.y);
  #pragma unroll
  for (int m=1; m<64; m<<=1){ s += __shfl_xor(s,m); sq += __shfl_xor(sq,m); }
  __shared__ float red[2][4];
  const int wid = tid>>6, lane = tid&63;
  if (lane==0){ red[0][wid]=s; red[1][wid]=sq; }
  __syncthreads();
  s  = red[0][0]+red[0][1]+red[0][2]+red[0][3];
  sq = red[1][0]+red[1][1]+red[1][2]+red[1][3];
  float mean = s*(1.0f/Dx);
  float var  = sq*(1.0f/Dx) - mean*mean;
  float rstd = rsqrtf(var + 1e-5f);
  float2 gg = *(const float2*)(g  + tid*2);
  float2 bb = *(const float2*)(be + tid*2);
  float2 o;
  o.x = (v.x-mean)*rstd*gg.x + bb.x;
  o.y = (v.y-mean)*rstd*gg.y + bb.y;
  if (Yf) *(float2*)(Yf + (size_t)row*Dx + tid*2) = o;
  if (Yb){
    ushort2 ob; ob.x = f2bf(o.x); ob.y = f2bf(o.y);
    *(ushort2*)(Yb + (size_t)row*Dx + tid*2) = ob;
  }
}

// ---------------------------------------------------------------------------
extern "C" void kernel_launch(void* const* d_in, const int* in_sizes, int n_in,
                              void* d_out, int out_size, void* d_ws, size_t ws_size,
                              hipStream_t stream)
{
  const float* Q    = (const float*)d_in[0];
  const float* K    = (const float*)d_in[1];
  const float* Kpos = (const float*)d_in[2];
  const float* Wq   = (const float*)d_in[3];
  const float* bq   = (const float*)d_in[4];
  const float* Wk   = (const float*)d_in[5];
  const float* bk   = (const float*)d_in[6];
  const float* Wv   = (const float*)d_in[7];
  const float* bv   = (const float*)d_in[8];
  const float* kp   = (const float*)d_in[9];
  const float* vp   = (const float*)d_in[10];
  const float* W0   = (const float*)d_in[11];
  const float* b0   = (const float*)d_in[12];
  const float* W1   = (const float*)d_in[13];
  const float* b1   = (const float*)d_in[14];
  const float* g0   = (const float*)d_in[15];
  const float* be0  = (const float*)d_in[16];
  const float* g1   = (const float*)d_in[17];
  const float* be1  = (const float*)d_in[18];
  float* out = (float*)d_out;
  char* wsb  = (char*)d_ws;

  const size_t MB = 1024*1024;
  unsigned short* Qp  = (unsigned short*)(wsb);          // 8 MiB bf16 [8192][512]
  unsigned short* Kp  = (unsigned short*)(wsb + 8*MB);   // pre-scaled (log2e/sqrt512)
  unsigned short* Vp  = (unsigned short*)(wsb + 16*MB);
  float*          O0  = (float*)         (wsb + 24*MB);  // 16 MiB f32
  unsigned short* Vpt = (unsigned short*)(wsb + 40*MB);  // 8 MiB
  unsigned short* O0b = (unsigned short*)(wsb + 48*MB);  // 8 MiB
  unsigned short* Wt  = (unsigned short*)(wsb + 56*MB);  // 2.5 MiB [5][512][512]
  unsigned short* T1  = Vp;                              // reuse after vt

  const float kscale = 0.044194173824159216f * 1.4426950408889634f; // log2e/sqrt(512)

  // weight transposes (Wq,Wk,Wv,W0,W1)
  mab_wt<<<dim3(8,8,5), 256, 0, stream>>>(Wq, Wk, Wv, W0, W1, Wt);
  // fused Q/K/V projections from f32 inputs (z=0,1,2)
  mab_gemm_proj<<<dim3(4,64,3), 256, 0, stream>>>(Q, K, Wt, bq, bk, bv, Qp, kscale);
  // V transpose to d-major
  mab_vt<<<dim3(32,8,4), 256, 0, stream>>>(Vp, Vpt);
  // fused attention (32x32 swapped structure, exp2 domain)
  mab_attn2<<<dim3(16,8,4), 256, 0, stream>>>(Qp, Kp, Vpt, Kpos, kp, vp, out);
  // LN0 -> O0 (f32) + O0b (bf16)
  mab_ln2<<<8192, 256, 0, stream>>>(out, g0, be0, O0, O0b);
  // T1 = relu(O0 @ W0 + b0)  (bf16 out)
  mab_gemm_mfma<<<dim3(4,64,1), 256, 0, stream>>>(
      O0b, Wt + (size_t)3*512*512, b0, nullptr, T1, nullptr, 1);
  // out = O0 + relu(T1 @ W1 + b1)  (f32 out)
  mab_gemm_mfma<<<dim3(4,64,1), 256, 0, stream>>>(
      T1, Wt + (size_t)4*512*512, b1, O0, nullptr, out, 1);
  // final LN in-place
  mab_ln2<<<8192, 256, 0, stream>>>(out, g1, be1, out, nullptr);
}